// Round 6
// baseline (1128.689 us; speedup 1.0000x reference)
//
#include <hip/hip_runtime.h>

#define NPTS   16384
#define KCODES 8192
#define DDIM   256
#define HWSZ   1024
#define CHW    (DDIM * HWSZ)          // 262144
#define OUT_ELEMS 4194304
#define LOSS_OFF  OUT_ELEMS
#define IDX_OFF   (OUT_ELEMS + 1)

#define PT 32            // points per block
#define KT 1024          // codes per pass
#define DK 8             // d-chunk staged in LDS
#define NPASS  (KCODES / KT)    // 8
#define NCHUNK (DDIM / DK)      // 32
#define NITER  (NPASS * NCHUNK) // 256
#define PW     (DK * KT)        // 8192 words, single-buffered pool
#define XP     36               // xT pitch (floats): 16B-aligned float4 at p0 in {0,8,16,24}

// e-tile swizzle: (d, k) -> pool[d*KT + ((((k>>2) ^ d) << 2) | (k&3))]
// NOTE: no second __launch_bounds__ arg — on this toolchain it acts like CUDA
// min-blocks/CU and capped VGPRs at 64 (R4: 3.8 GB spill traffic).
// x is read in the FMA loop from LDS with WAVE-UNIFORM addresses (broadcast,
// ~5 cyc, no VMEM latency) — R5's global x loads were 4KB-strided L1-thrashing
// L2 hits (~200 cyc) that stalled all barrier-synced waves together.

__launch_bounds__(512)
__global__ void vq_kernel(const float* __restrict__ x,
                          const float* __restrict__ emb,
                          float* __restrict__ out)
{
    __shared__ float  pool[PW];          // 32768 B: e chunk (swizzled transpose); prologue scratch
    __shared__ float  ldsXT[DDIM][XP];   // 36864 B: x tile transposed [c][p]
    __shared__ float  ldsSE[KT];         // 4096 B: ||e||^2 per code of current pass
    __shared__ float  ldsS[PT];
    __shared__ int    ldsI[PT];
    __shared__ float  ldsFD[64];         // 8 waves x 8 points: final argmin stage
    __shared__ int    ldsFI[64];
    __shared__ double ldsL[8];

    const int t   = threadIdx.x;
    const int n0  = blockIdx.x * PT;
    const int b   = n0 / HWSZ;
    const int hw0 = n0 % HWSZ;
    const float* xs = x + (size_t)b * CHW + hw0;   // xs[c*HWSZ + p] = x[b][c][hw0+p]

    const int kq = t >> 1;          // staging code base (0..255), +256*i
    const int dh = (t & 1) * 4;     // staging d-half {0,4}

    // ---- prefetch e chunk 0 ----
    float4 stg[4];
    {
        const float* src = emb + (size_t)kq * DDIM + dh;
        #pragma unroll
        for (int i = 0; i < 4; ++i)
            stg[i] = *(const float4*)(src + (size_t)i * 256 * DDIM);
    }

    // ---- stage x tile transposed: ldsXT[c][p] = x[b][c][hw0+p] ----
    {
        const int p   = t & 31;
        const int seg = t >> 5;                    // 0..15
        for (int i = 0; i < 16; ++i) {
            const int c = i * 16 + seg;
            ldsXT[c][p] = xs[(size_t)c * HWSZ + p];
        }
    }
    __syncthreads();

    // ---- prologue: s[p] = ||x_p||^2 (fp32 FMA; per-point-constant error cancels in argmin) ----
    {
        const int p   = t & 31;
        const int seg = t >> 5;
        float a = 0.0f;
        for (int i = 0; i < 16; ++i) {
            const float v = ldsXT[seg * 16 + i][p];
            a = fmaf(v, v, a);
        }
        pool[seg * 33 + p] = a;                    // pool as pre-loop scratch
    }
    __syncthreads();
    if (t < PT) {
        float s = 0.0f;
        for (int g = 0; g < 16; ++g) s += pool[g * 33 + t];
        ldsS[t] = s;
    }
    // no barrier needed here: chunk-0 barrier-1 orders pool reuse; ldsS read much later

    const int kg = t & 127;                        // codes 4kg..4kg+3 (L), +512 (H)
    const int p0 = (t >> 7) * 8;                   // 8 points, wave-uniform value

    float best_d[8];
    int   best_i[8];
    #pragma unroll
    for (int i = 0; i < 8; ++i) { best_d[i] = 3.4e38f; best_i[i] = 0; }

    float4 accL[8], accH[8];
    float  se_reg[4] = {0.f, 0.f, 0.f, 0.f};

    for (int c = 0; c < NITER; ++c) {
        if ((c & 31) == 0) {
            #pragma unroll
            for (int i = 0; i < 8; ++i) {
                accL[i] = make_float4(0.f, 0.f, 0.f, 0.f);
                accH[i] = make_float4(0.f, 0.f, 0.f, 0.f);
            }
        }
        __syncthreads();   // barrier 1: prior chunk's pool readers done
        // ---- stage chunk c from regs into swizzled transpose; SE reg accumulate ----
        #pragma unroll
        for (int i = 0; i < 4; ++i) {
            const int k = kq + 256 * i;            // local code 0..1023
            const int g = k >> 2;
            const int m = k & 3;
            const float4 v = stg[i];
            pool[(dh + 0) * KT + (((g ^ (dh + 0)) << 2) | m)] = v.x;
            pool[(dh + 1) * KT + (((g ^ (dh + 1)) << 2) | m)] = v.y;
            pool[(dh + 2) * KT + (((g ^ (dh + 2)) << 2) | m)] = v.z;
            pool[(dh + 3) * KT + (((g ^ (dh + 3)) << 2) | m)] = v.w;
            float ps = v.x * v.x;
            ps = fmaf(v.y, v.y, ps);
            ps = fmaf(v.z, v.z, ps);
            ps = fmaf(v.w, v.w, ps);
            se_reg[i] += ps;
        }
        if ((c & 31) == 31) {                      // pass's last chunk: publish SE
            #pragma unroll
            for (int i = 0; i < 4; ++i) {
                const float tot = se_reg[i] + __shfl_xor(se_reg[i], 1);
                if ((t & 1) == 0) ldsSE[kq + 256 * i] = tot;
                se_reg[i] = 0.f;
            }
        }
        __syncthreads();   // barrier 2: staged tile + SE visible
        // ---- prefetch chunk c+1 (post-barrier; a full chunk of slack to land) ----
        {
            int nc = c + 1;
            if (nc == NITER) nc = 0;               // harmless dummy
            const int npass = nc >> 5, nch = nc & 31;
            const float* src = emb + ((size_t)(npass * KT + kq) * DDIM) + nch * DK + dh;
            #pragma unroll
            for (int i = 0; i < 4; ++i)
                stg[i] = *(const float4*)(src + (size_t)i * 256 * DDIM);
        }
        // ---- compute chunk c: 8 pts x 8 codes x 8 d; x via uniform LDS broadcasts ----
        {
            const int chd = (c & 31) * DK;
            #pragma unroll
            for (int dd = 0; dd < 8; ++dd) {
                const int go = (kg ^ dd) << 2;
                const float4 eL = *(const float4*)&pool[dd * KT + go];
                const float4 eH = *(const float4*)&pool[dd * KT + go + 512];
                const float4 xa = *(const float4*)&ldsXT[chd + dd][p0];      // p0..p0+3
                const float4 xb = *(const float4*)&ldsXT[chd + dd][p0 + 4];  // p0+4..p0+7
                #pragma unroll
                for (int p = 0; p < 4; ++p) {
                    const float xsc = ((const float*)&xa)[p];
                    accL[p].x = fmaf(xsc, eL.x, accL[p].x);
                    accL[p].y = fmaf(xsc, eL.y, accL[p].y);
                    accL[p].z = fmaf(xsc, eL.z, accL[p].z);
                    accL[p].w = fmaf(xsc, eL.w, accL[p].w);
                    accH[p].x = fmaf(xsc, eH.x, accH[p].x);
                    accH[p].y = fmaf(xsc, eH.y, accH[p].y);
                    accH[p].z = fmaf(xsc, eH.z, accH[p].z);
                    accH[p].w = fmaf(xsc, eH.w, accH[p].w);
                }
                #pragma unroll
                for (int p = 4; p < 8; ++p) {
                    const float xsc = ((const float*)&xb)[p - 4];
                    accL[p].x = fmaf(xsc, eL.x, accL[p].x);
                    accL[p].y = fmaf(xsc, eL.y, accL[p].y);
                    accL[p].z = fmaf(xsc, eL.z, accL[p].z);
                    accL[p].w = fmaf(xsc, eL.w, accL[p].w);
                    accH[p].x = fmaf(xsc, eH.x, accH[p].x);
                    accH[p].y = fmaf(xsc, eH.y, accH[p].y);
                    accH[p].z = fmaf(xsc, eH.z, accH[p].z);
                    accH[p].w = fmaf(xsc, eH.w, accH[p].w);
                }
            }
        }
        // ---- pass finalize: dist = fl(fl(s+se) - 2m), ascending code index ----
        if ((c & 31) == 31) {
            const int kbase = (c >> 5) * KT;
            #pragma unroll
            for (int j = 0; j < 4; ++j) {          // L half first (smaller indices)
                const float se = ldsSE[4 * kg + j];
                const int   ki = kbase + 4 * kg + j;
                #pragma unroll
                for (int i = 0; i < 8; ++i) {
                    const float T = ldsS[p0 + i] + se;
                    const float d = fmaf(-2.0f, ((const float*)&accL[i])[j], T);
                    if (d < best_d[i]) { best_d[i] = d; best_i[i] = ki; }
                }
            }
            #pragma unroll
            for (int j = 0; j < 4; ++j) {          // H half
                const float se = ldsSE[512 + 4 * kg + j];
                const int   ki = kbase + 512 + 4 * kg + j;
                #pragma unroll
                for (int i = 0; i < 8; ++i) {
                    const float T = ldsS[p0 + i] + se;
                    const float d = fmaf(-2.0f, ((const float*)&accH[i])[j], T);
                    if (d < best_d[i]) { best_d[i] = d; best_i[i] = ki; }
                }
            }
        }
    }

    // ---- wave butterfly argmin (lexicographic), then cross-wave via LDS ----
    #pragma unroll
    for (int off = 1; off < 64; off <<= 1) {
        #pragma unroll
        for (int i = 0; i < 8; ++i) {
            const float d2 = __shfl_xor(best_d[i], off);
            const int   i2 = __shfl_xor(best_i[i], off);
            if (d2 < best_d[i] || (d2 == best_d[i] && i2 < best_i[i])) {
                best_d[i] = d2; best_i[i] = i2;
            }
        }
    }
    if ((t & 63) == 0) {
        const int w = t >> 6;
        #pragma unroll
        for (int i = 0; i < 8; ++i) { ldsFD[w * 8 + i] = best_d[i]; ldsFI[w * 8 + i] = best_i[i]; }
    }
    __syncthreads();
    if (t < PT) {
        const int pg = t >> 3, i = t & 7;
        float bd = ldsFD[(2 * pg) * 8 + i];
        int   bi = ldsFI[(2 * pg) * 8 + i];
        const float d2 = ldsFD[(2 * pg + 1) * 8 + i];
        const int   i2 = ldsFI[(2 * pg + 1) * 8 + i];
        if (d2 < bd || (d2 == bd && i2 < bi)) { bd = d2; bi = i2; }
        ldsI[t] = bi;
        out[(size_t)IDX_OFF + n0 + t] = (float)bi;
    }
    __syncthreads();

    // ---- epilogue: gather e row, straight-through out, loss partial ----
    double lsum = 0.0;
    {
        const int p  = t & 31;
        const int cg = t >> 5;                     // 0..15
        const int row = ldsI[p];
        const float* erow = emb + (size_t)row * DDIM;
        float* ob = out + (size_t)b * CHW + hw0 + p;
        for (int q = 0; q < 16; ++q) {
            const int c = cg * 16 + q;
            const float e  = erow[c];
            const float xx = xs[(size_t)c * HWSZ + p];
            const float diff = e - xx;             // fl(x_q - xt)
            ob[(size_t)c * HWSZ] = xx + diff;      // straight-through rounding
            lsum += (double)diff * (double)diff;
        }
    }
    #pragma unroll
    for (int off = 32; off > 0; off >>= 1)
        lsum += __shfl_xor(lsum, off);
    if ((t & 63) == 0) ldsL[t >> 6] = lsum;
    __syncthreads();
    if (t == 0) {
        double tot = 0.0;
        #pragma unroll
        for (int wv = 0; wv < 8; ++wv) tot += ldsL[wv];
        atomicAdd(&out[LOSS_OFF], (float)(tot * (1.25 / 4194304.0)));
    }
}

extern "C" void kernel_launch(void* const* d_in, const int* in_sizes, int n_in,
                              void* d_out, int out_size, void* d_ws, size_t ws_size,
                              hipStream_t stream) {
    (void)in_sizes; (void)n_in; (void)ws_size; (void)d_ws; (void)out_size;
    const float* x   = (const float*)d_in[0];
    const float* emb = (const float*)d_in[1];
    float* out = (float*)d_out;
    hipMemsetAsync((char*)d_out + (size_t)LOSS_OFF * sizeof(float), 0, sizeof(float), stream);
    vq_kernel<<<NPTS / PT, 512, 0, stream>>>(x, emb, out);
}

// Round 7
// 403.211 us; speedup vs baseline: 2.7993x; 2.7993x over previous
//
#include <hip/hip_runtime.h>

#define NPTS   16384
#define KCODES 8192
#define DDIM   256
#define HWSZ   1024
#define CHW    (DDIM * HWSZ)          // 262144
#define OUT_ELEMS 4194304
#define LOSS_OFF  OUT_ELEMS
#define IDX_OFF   (OUT_ELEMS + 1)

#define PTB   64                 // points per block
#define CTILE 128                // codes per tile
#define NTILE (KCODES / CTILE)   // 64
#define KC    64                 // k per staged chunk
#define NIT   (NTILE * (DDIM / KC))  // 256
#define XPITCH 264               // f16 pitch, 528 B (132 banks = 4 mod 32 -> 2-way)
#define EPITCH 72                // f16 pitch, 144 B (36 banks  = 4 mod 32 -> 2-way)

typedef _Float16 half_t;
typedef __attribute__((ext_vector_type(8))) _Float16 half8;
typedef __attribute__((ext_vector_type(4))) float     v4f;

union HU  { _Float16 h;    unsigned short u; };
union H2U { _Float16 h[2]; unsigned int   u; };

// m = x.e computed as 3 f16 MFMAs with exact pow2 scalings:
//   E = 64*e; eh=f16(E); el=f16((E-eh)*2048); xh=f16(x); xl=f16((x-xh)*2048)
//   m = (hh + (hl+lh)*2^-11) / 64 ; dropped ll + residues ~1e-6 (same noise
//   class as the reordered fp32 chains that passed R1-R6).
// dist = fl(fl(s+se) - 2m) in fp32 with lowest-index tie-break (unchanged).
// NOTE: never pass a second __launch_bounds__ arg on this toolchain (R4).

__launch_bounds__(512)
__global__ void vq_kernel(const float* __restrict__ x,
                          const float* __restrict__ emb,
                          float* __restrict__ out)
{
    __shared__ __align__(16) unsigned short ldsXH[PTB][XPITCH];       // 33792 B
    __shared__ __align__(16) unsigned short ldsXL[PTB][XPITCH];       // 33792 B
    __shared__ __align__(16) unsigned short ldsEH[2][CTILE][EPITCH];  // 36864 B
    __shared__ __align__(16) unsigned short ldsEL[2][CTILE][EPITCH];  // 36864 B
    __shared__ float  ldsSE[CTILE];
    __shared__ float  ldsS[PTB];
    __shared__ float  ldsRS[8][65];
    __shared__ float  ldsFD[8][32];
    __shared__ int    ldsFI[8][32];
    __shared__ int    ldsI[PTB];
    __shared__ double ldsL[8];

    const int t   = threadIdx.x;
    const int n0  = blockIdx.x * PTB;
    const int b   = n0 / HWSZ;
    const int hw0 = n0 % HWSZ;
    const float* xs = x + (size_t)b * CHW + hw0;   // xs[c*HWSZ + p]

    // e-staging map: 4 threads per code; thread covers k-slots ((t&3)+4i)*4
    const int ecode = t >> 2;
    const int eslot = t & 3;

    // ---- prefetch e chunk 0 (tile 0, ck 0) ----
    float4 stg[4];
    {
        const float* src = emb + (size_t)ecode * DDIM + eslot * 4;
        #pragma unroll
        for (int i = 0; i < 4; ++i) stg[i] = *(const float4*)(src + i * 16);
    }

    // ---- prologue: stage x split hi/lo (f16), accumulate s[p]=||x_p||^2 ----
    {
        const int p   = t & 63;
        const int seg = t >> 6;                    // 8 segs x 32 channels
        float a = 0.f;
        for (int i = 0; i < 32; ++i) {
            const int c = seg * 32 + i;
            const float v = xs[(size_t)c * HWSZ + p];
            const half_t hh = (half_t)v;
            const half_t hl = (half_t)((v - (float)hh) * 2048.0f);
            HU u0; u0.h = hh; ldsXH[p][c] = u0.u;
            HU u1; u1.h = hl; ldsXL[p][c] = u1.u;
            a = fmaf(v, v, a);
        }
        ldsRS[seg][p] = a;
    }
    __syncthreads();
    if (t < PTB) {
        float s = 0.f;
        for (int g = 0; g < 8; ++g) s += ldsRS[g][t];
        ldsS[t] = s;
    }
    __syncthreads();

    const int lane = t & 63;
    const int w    = t >> 6;          // 0..7
    const int h32  = (w & 1) * 32;    // pt-half base row
    const int q32  = (w >> 1) * 32;   // code-quarter base within tile
    const int ln   = lane & 15;
    const int qd   = lane >> 4;       // 0..3

    float s_frag[8];
    #pragma unroll
    for (int pbi = 0; pbi < 2; ++pbi)
        #pragma unroll
        for (int r = 0; r < 4; ++r)
            s_frag[pbi * 4 + r] = ldsS[h32 + pbi * 16 + qd * 4 + r];

    float best_d[8]; int best_i[8];
    #pragma unroll
    for (int i = 0; i < 8; ++i) { best_d[i] = 3.4e38f; best_i[i] = 0; }

    v4f acc_hh[2][2], acc_hl[2][2];
    float se_reg = 0.f;

    for (int it = 0; it < NIT; ++it) {
        const int ck  = it & 3;
        const int buf = it & 1;
        if (ck == 0) {
            #pragma unroll
            for (int i = 0; i < 2; ++i)
                #pragma unroll
                for (int j = 0; j < 2; ++j)
                    #pragma unroll
                    for (int r = 0; r < 4; ++r) { acc_hh[i][j][r] = 0.f; acc_hl[i][j][r] = 0.f; }
        }
        // ---- stage chunk from regs: split to f16 hi/lo; se accumulate ----
        #pragma unroll
        for (int i = 0; i < 4; ++i) {
            const float4 v = stg[i];
            const int k0 = (eslot + 4 * i) * 4;    // f16 index within chunk row
            float ps = v.x * v.x;
            ps = fmaf(v.y, v.y, ps); ps = fmaf(v.z, v.z, ps); ps = fmaf(v.w, v.w, ps);
            se_reg += ps;
            const float E0 = v.x * 64.f, E1 = v.y * 64.f, E2 = v.z * 64.f, E3 = v.w * 64.f;
            const half_t h0 = (half_t)E0, h1 = (half_t)E1, h2 = (half_t)E2, h3 = (half_t)E3;
            const half_t l0 = (half_t)((E0 - (float)h0) * 2048.f);
            const half_t l1 = (half_t)((E1 - (float)h1) * 2048.f);
            const half_t l2 = (half_t)((E2 - (float)h2) * 2048.f);
            const half_t l3 = (half_t)((E3 - (float)h3) * 2048.f);
            H2U a; a.h[0] = h0; a.h[1] = h1;
            H2U c; c.h[0] = h2; c.h[1] = h3;
            H2U d; d.h[0] = l0; d.h[1] = l1;
            H2U e; e.h[0] = l2; e.h[1] = l3;
            *(unsigned int*)&ldsEH[buf][ecode][k0]     = a.u;
            *(unsigned int*)&ldsEH[buf][ecode][k0 + 2] = c.u;
            *(unsigned int*)&ldsEL[buf][ecode][k0]     = d.u;
            *(unsigned int*)&ldsEL[buf][ecode][k0 + 2] = e.u;
        }
        if (ck == 3) {                              // publish se for this tile
            float tot = se_reg;
            tot += __shfl_xor(tot, 1);
            tot += __shfl_xor(tot, 2);
            if ((t & 3) == 0) ldsSE[ecode] = tot;
            se_reg = 0.f;
        }
        __syncthreads();   // single barrier per chunk (double-buffered e-tile)
        // ---- prefetch next chunk ----
        {
            int nit = it + 1; if (nit == NIT) nit = 0;
            const int ntile = nit >> 2, nck = nit & 3;
            const float* src = emb + ((size_t)(ntile * CTILE + ecode)) * DDIM + nck * KC + eslot * 4;
            #pragma unroll
            for (int i = 0; i < 4; ++i) stg[i] = *(const float4*)(src + i * 16);
        }
        // ---- MFMA: 32 pts x 32 codes, K=64 via 2 K32 steps x 3 splits x 2x2 tiles ----
        #pragma unroll
        for (int kk = 0; kk < 2; ++kk) {
            const int ka = ck * KC + kk * 32 + qd * 8;   // k into x rows
            const int kb = kk * 32 + qd * 8;             // k into e rows (chunk-local)
            const half8 ah0 = *(const half8*)&ldsXH[h32 + ln][ka];
            const half8 ah1 = *(const half8*)&ldsXH[h32 + 16 + ln][ka];
            const half8 al0 = *(const half8*)&ldsXL[h32 + ln][ka];
            const half8 al1 = *(const half8*)&ldsXL[h32 + 16 + ln][ka];
            const half8 bh0 = *(const half8*)&ldsEH[buf][q32 + ln][kb];
            const half8 bh1 = *(const half8*)&ldsEH[buf][q32 + 16 + ln][kb];
            const half8 bl0 = *(const half8*)&ldsEL[buf][q32 + ln][kb];
            const half8 bl1 = *(const half8*)&ldsEL[buf][q32 + 16 + ln][kb];
            acc_hh[0][0] = __builtin_amdgcn_mfma_f32_16x16x32_f16(ah0, bh0, acc_hh[0][0], 0, 0, 0);
            acc_hh[0][1] = __builtin_amdgcn_mfma_f32_16x16x32_f16(ah0, bh1, acc_hh[0][1], 0, 0, 0);
            acc_hh[1][0] = __builtin_amdgcn_mfma_f32_16x16x32_f16(ah1, bh0, acc_hh[1][0], 0, 0, 0);
            acc_hh[1][1] = __builtin_amdgcn_mfma_f32_16x16x32_f16(ah1, bh1, acc_hh[1][1], 0, 0, 0);
            acc_hl[0][0] = __builtin_amdgcn_mfma_f32_16x16x32_f16(ah0, bl0, acc_hl[0][0], 0, 0, 0);
            acc_hl[0][1] = __builtin_amdgcn_mfma_f32_16x16x32_f16(ah0, bl1, acc_hl[0][1], 0, 0, 0);
            acc_hl[1][0] = __builtin_amdgcn_mfma_f32_16x16x32_f16(ah1, bl0, acc_hl[1][0], 0, 0, 0);
            acc_hl[1][1] = __builtin_amdgcn_mfma_f32_16x16x32_f16(ah1, bl1, acc_hl[1][1], 0, 0, 0);
            acc_hl[0][0] = __builtin_amdgcn_mfma_f32_16x16x32_f16(al0, bh0, acc_hl[0][0], 0, 0, 0);
            acc_hl[0][1] = __builtin_amdgcn_mfma_f32_16x16x32_f16(al0, bh1, acc_hl[0][1], 0, 0, 0);
            acc_hl[1][0] = __builtin_amdgcn_mfma_f32_16x16x32_f16(al1, bh0, acc_hl[1][0], 0, 0, 0);
            acc_hl[1][1] = __builtin_amdgcn_mfma_f32_16x16x32_f16(al1, bh1, acc_hl[1][1], 0, 0, 0);
        }
        // ---- tile finalize: dist = fl(fl(s+se) - 2m), ascending code order ----
        if (ck == 3) {
            const int tb = (it >> 2) * CTILE;
            #pragma unroll
            for (int csi = 0; csi < 2; ++csi) {    // csi=0 first (smaller codes)
                const float se   = ldsSE[q32 + csi * 16 + ln];
                const int   code = tb + q32 + csi * 16 + ln;
                #pragma unroll
                for (int pbi = 0; pbi < 2; ++pbi)
                    #pragma unroll
                    for (int r = 0; r < 4; ++r) {
                        const float m  = fmaf(acc_hl[pbi][csi][r], 4.8828125e-4f,
                                              acc_hh[pbi][csi][r]) * 0.015625f;
                        const float T  = s_frag[pbi * 4 + r] + se;
                        const float dd = fmaf(-2.0f, m, T);
                        const int   s  = pbi * 4 + r;
                        if (dd < best_d[s]) { best_d[s] = dd; best_i[s] = code; }
                    }
            }
        }
    }

    // ---- argmin reduce: butterfly over the 16-lane col group (lexicographic) ----
    #pragma unroll
    for (int off = 1; off < 16; off <<= 1) {
        #pragma unroll
        for (int s = 0; s < 8; ++s) {
            const float d2 = __shfl_xor(best_d[s], off);
            const int   i2 = __shfl_xor(best_i[s], off);
            if (d2 < best_d[s] || (d2 == best_d[s] && i2 < best_i[s])) {
                best_d[s] = d2; best_i[s] = i2;
            }
        }
    }
    if (ln == 0) {
        #pragma unroll
        for (int pbi = 0; pbi < 2; ++pbi)
            #pragma unroll
            for (int r = 0; r < 4; ++r) {
                ldsFD[w][pbi * 16 + qd * 4 + r] = best_d[pbi * 4 + r];
                ldsFI[w][pbi * 16 + qd * 4 + r] = best_i[pbi * 4 + r];
            }
    }
    __syncthreads();
    if (t < PTB) {
        const int hh  = t >> 5;
        const int r32 = t & 31;
        float bd = 3.4e38f; int bi = 0;
        #pragma unroll
        for (int qq = 0; qq < 4; ++qq) {
            const int wv = hh + qq * 2;
            const float d2 = ldsFD[wv][r32];
            const int   i2 = ldsFI[wv][r32];
            if (d2 < bd || (d2 == bd && i2 < bi)) { bd = d2; bi = i2; }
        }
        ldsI[t] = bi;
        out[(size_t)IDX_OFF + n0 + t] = (float)bi;
    }
    __syncthreads();

    // ---- epilogue: gather e row, straight-through out, loss partial ----
    double lsum = 0.0;
    {
        const int p  = t & 63;
        const int cg = t >> 6;                     // 8 groups x 32 channels
        const int row = ldsI[p];
        const float* erow = emb + (size_t)row * DDIM;
        float* ob = out + (size_t)b * CHW + hw0 + p;
        for (int q = 0; q < 32; ++q) {
            const int c = cg * 32 + q;
            const float e  = erow[c];
            const float xx = xs[(size_t)c * HWSZ + p];
            const float diff = e - xx;             // fl(x_q - xt)
            ob[(size_t)c * HWSZ] = xx + diff;      // straight-through rounding
            lsum += (double)diff * (double)diff;
        }
    }
    #pragma unroll
    for (int off = 32; off > 0; off >>= 1)
        lsum += __shfl_xor(lsum, off);
    if ((t & 63) == 0) ldsL[t >> 6] = lsum;
    __syncthreads();
    if (t == 0) {
        double tot = 0.0;
        #pragma unroll
        for (int wv = 0; wv < 8; ++wv) tot += ldsL[wv];
        atomicAdd(&out[LOSS_OFF], (float)(tot * (1.25 / 4194304.0)));
    }
}

extern "C" void kernel_launch(void* const* d_in, const int* in_sizes, int n_in,
                              void* d_out, int out_size, void* d_ws, size_t ws_size,
                              hipStream_t stream) {
    (void)in_sizes; (void)n_in; (void)ws_size; (void)d_ws; (void)out_size;
    const float* x   = (const float*)d_in[0];
    const float* emb = (const float*)d_in[1];
    float* out = (float*)d_out;
    hipMemsetAsync((char*)d_out + (size_t)LOSS_OFF * sizeof(float), 0, sizeof(float), stream);
    vq_kernel<<<NPTS / PTB, 512, 0, stream>>>(x, emb, out);
}

// Round 9
// 318.894 us; speedup vs baseline: 3.5394x; 1.2644x over previous
//
#include <hip/hip_runtime.h>

#define NPTS   16384
#define KCODES 8192
#define DDIM   256
#define HWSZ   1024
#define CHW    (DDIM * HWSZ)          // 262144
#define OUT_ELEMS 4194304
#define LOSS_OFF  OUT_ELEMS
#define IDX_OFF   (OUT_ELEMS + 1)

#define PTB   64                 // points per block
#define CTILE 128                // codes per tile
#define KC    64                 // k per staged chunk
#define NIT   256                // 64 tiles x 4 chunks; image index == it
#define XPITCH 264               // x f16 pitch (528 B = 4 mod 32 banks -> 2-way, free)

typedef _Float16 half_t;
typedef __attribute__((ext_vector_type(8))) _Float16 half8;
typedef __attribute__((ext_vector_type(4))) float     v4f;

union HU { _Float16 h; unsigned short u; };

// ws layout: ehi[256 images][128 codes][64 ushort] (16 KB/image, 4 MB),
//            elo same (4 MB), se[8192] f32. Images pre-swizzled: row r,
//            16B-block kb stored at block (kb ^ (r&7)) -> LDS fragment reads
//            are 2-way bank-aliased (free) with zero padding, and staging is
//            a pure linear DMA via global_load_lds (no VALU, no conflicts).
#define EHI_WORDS  (256 * 8192)                 // ushorts
#define SE_OFF_B   (2 * EHI_WORDS * 2)          // byte offset of se[] in ws

#define GLD16(gp, lp) __builtin_amdgcn_global_load_lds( \
    (const __attribute__((address_space(1))) unsigned int*)(gp), \
    (__attribute__((address_space(3))) unsigned int*)(lp), 16, 0, 0)

// ---- prep: split emb to f16 hi/lo (bit-identical formula to R7 staging),
// ---- pre-swizzled image layout, plus se[k] = ||e_k||^2 (fp32) ----
// Coverage: 256 blocks x 4 waves = 1024 waves x 8 codes = 8192 codes.
// (R8 BUG: launched 32 blocks -> only codes 0..1023 prepped, rest poison.)
__global__ void prep_kernel(const float* __restrict__ emb,
                            unsigned short* __restrict__ ehi,
                            unsigned short* __restrict__ elo,
                            float* __restrict__ se)
{
    const int gw   = (blockIdx.x * 256 + threadIdx.x) >> 6;   // 0..1023
    const int lane = threadIdx.x & 63;
    for (int i = 0; i < 8; ++i) {
        const int c = gw * 8 + i;                             // code 0..8191
        const float4 v = *(const float4*)(emb + (size_t)c * DDIM + lane * 4);
        float ps = v.x * v.x;
        ps = fmaf(v.y, v.y, ps); ps = fmaf(v.z, v.z, ps); ps = fmaf(v.w, v.w, ps);
        float tot = ps;
        #pragma unroll
        for (int off = 1; off < 64; off <<= 1) tot += __shfl_xor(tot, off);
        if (lane == 0) se[c] = tot;
        const float E0 = v.x * 64.f, E1 = v.y * 64.f, E2 = v.z * 64.f, E3 = v.w * 64.f;
        const half_t h0 = (half_t)E0, h1 = (half_t)E1, h2 = (half_t)E2, h3 = (half_t)E3;
        const half_t l0 = (half_t)((E0 - (float)h0) * 2048.f);
        const half_t l1 = (half_t)((E1 - (float)h1) * 2048.f);
        const half_t l2 = (half_t)((E2 - (float)h2) * 2048.f);
        const half_t l3 = (half_t)((E3 - (float)h3) * 2048.f);
        HU a0, a1, a2, a3, b0, b1, b2, b3;
        a0.h = h0; a1.h = h1; a2.h = h2; a3.h = h3;
        b0.h = l0; b1.h = l1; b2.h = l2; b3.h = l3;
        const unsigned int uh0 = (unsigned)a0.u | ((unsigned)a1.u << 16);
        const unsigned int uh1 = (unsigned)a2.u | ((unsigned)a3.u << 16);
        const unsigned int ul0 = (unsigned)b0.u | ((unsigned)b1.u << 16);
        const unsigned int ul1 = (unsigned)b2.u | ((unsigned)b3.u << 16);
        const int ck = lane >> 4;                 // chunk 0..3 (k block of 64)
        const int kb = (lane & 15) >> 1;          // 16B block within row, 0..7
        const int hf = lane & 1;                  // half-block
        const int T = c >> 7, r = c & 127;
        const size_t base = (((size_t)(T * 4 + ck) * 128 + r) * 64)
                          + (size_t)((kb ^ (r & 7)) * 8) + hf * 4;
        *(unsigned int*)&ehi[base]     = uh0;
        *(unsigned int*)&ehi[base + 2] = uh1;
        *(unsigned int*)&elo[base]     = ul0;
        *(unsigned int*)&elo[base + 2] = ul1;
    }
}

// m = x.e via 3 f16 MFMAs (exact pow2 scalings, R7-identical):
//   m = (hh + (xh.el + xl.eh)*2^-11) / 64
// dist = fl(fl(s+se) - 2m) fp32, lowest-index tie-break (proven R1-R7).
// NOTE: never pass a second __launch_bounds__ arg on this toolchain (R4).
__launch_bounds__(512)
__global__ void vq_kernel(const float* __restrict__ x,
                          const unsigned short* __restrict__ ehi,
                          const unsigned short* __restrict__ elo,
                          const float* __restrict__ wse,
                          const float* __restrict__ emb,
                          float* __restrict__ out)
{
    __shared__ __align__(16) unsigned short ldsXH[PTB][XPITCH];   // 33792 B
    __shared__ __align__(16) unsigned short ldsXL[PTB][XPITCH];   // 33792 B
    __shared__ __align__(16) unsigned short ldsEH[2][8192];       // 32768 B
    __shared__ __align__(16) unsigned short ldsEL[2][8192];       // 32768 B
    __shared__ float  ldsRS[8][65];
    __shared__ float  ldsS[PTB];
    __shared__ float  ldsFD[8][32];
    __shared__ int    ldsFI[8][32];
    __shared__ int    ldsI[PTB];
    __shared__ double ldsL[8];

    const int t    = threadIdx.x;
    const int lane = t & 63;
    const int w    = t >> 6;          // 0..7
    const int n0   = blockIdx.x * PTB;
    const int b    = n0 / HWSZ;
    const int hw0  = n0 % HWSZ;
    const float* xs = x + (size_t)b * CHW + hw0;   // xs[c*HWSZ + p]

    // ---- e-chunk DMA staging: 32 KB/iter; waves 0-3 hi, 4-7 lo; 4x1KB calls ----
    const int part = (w & 3) * 4096;               // byte sub-range
    #define STAGE(img, buf) do { \
        const char* _g = (const char*)((w < 4) ? ehi : elo) \
                       + (size_t)(img) * 16384 + part + lane * 16; \
        char* _l = (char*)((w < 4) ? ldsEH[buf] : ldsEL[buf]) + part; \
        GLD16(_g,          _l); \
        GLD16(_g + 1024,   _l + 1024); \
        GLD16(_g + 2048,   _l + 2048); \
        GLD16(_g + 3072,   _l + 3072); \
    } while (0)

    STAGE(0, 0);   // bootstrap chunk 0 (drained by prologue barrier)

    // ---- prologue: stage x split hi/lo (f16), accumulate s[p]=||x_p||^2 ----
    {
        const int p   = t & 63;
        const int seg = t >> 6;
        float a = 0.f;
        for (int i = 0; i < 32; ++i) {
            const int c = seg * 32 + i;
            const float v = xs[(size_t)c * HWSZ + p];
            const half_t hh = (half_t)v;
            const half_t hl = (half_t)((v - (float)hh) * 2048.0f);
            HU u0; u0.h = hh; ldsXH[p][c] = u0.u;
            HU u1; u1.h = hl; ldsXL[p][c] = u1.u;
            a = fmaf(v, v, a);
        }
        ldsRS[seg][p] = a;
    }
    __syncthreads();
    if (t < PTB) {
        float s = 0.f;
        for (int g = 0; g < 8; ++g) s += ldsRS[g][t];
        ldsS[t] = s;
    }
    __syncthreads();

    const int h32 = (w & 1) * 32;     // pt-half base row
    const int q32 = (w >> 1) * 32;    // code-quarter base within tile
    const int ln  = lane & 15;
    const int qd  = lane >> 4;        // 0..3

    float s_frag[8];
    #pragma unroll
    for (int pbi = 0; pbi < 2; ++pbi)
        #pragma unroll
        for (int r = 0; r < 4; ++r)
            s_frag[pbi * 4 + r] = ldsS[h32 + pbi * 16 + qd * 4 + r];

    float best_d[8]; int best_i[8];
    #pragma unroll
    for (int i = 0; i < 8; ++i) { best_d[i] = 3.4e38f; best_i[i] = 0; }

    v4f acc_hh[2][2], acc_hl[2][2];
    float se0 = 0.f, se1 = 0.f;

    for (int it = 0; it < NIT; ++it) {
        const int ck  = it & 3;
        const int buf = it & 1;
        if (ck == 0) {
            #pragma unroll
            for (int i = 0; i < 2; ++i)
                #pragma unroll
                for (int j = 0; j < 2; ++j)
                    #pragma unroll
                    for (int r = 0; r < 4; ++r) { acc_hh[i][j][r] = 0.f; acc_hl[i][j][r] = 0.f; }
        }
        __syncthreads();   // buf[it&1] DMA drained; prior readers of buf[(it+1)&1] done
        if (it + 1 < NIT) STAGE(it + 1, (it + 1) & 1);   // async under compute
        if (ck == 2) {     // prefetch se for this tile's finalize (L2-hot 32 KB)
            const int tb2 = (it >> 2) * CTILE;
            se0 = wse[tb2 + q32 + ln];
            se1 = wse[tb2 + q32 + 16 + ln];
        }
        // ---- MFMA: 32 pts x 32 codes, K=64 via 2 K32 steps x 3 splits x 2x2 ----
        #pragma unroll
        for (int kk = 0; kk < 2; ++kk) {
            const int ka  = ck * KC + kk * 32 + qd * 8;          // k into x rows
            const int swz = ((kk * 4 + qd) ^ (ln & 7)) * 8;      // swizzled e block
            const int rL  = (q32 + ln) * 64;
            const int rH  = (q32 + 16 + ln) * 64;
            const half8 ah0 = *(const half8*)&ldsXH[h32 + ln][ka];
            const half8 ah1 = *(const half8*)&ldsXH[h32 + 16 + ln][ka];
            const half8 al0 = *(const half8*)&ldsXL[h32 + ln][ka];
            const half8 al1 = *(const half8*)&ldsXL[h32 + 16 + ln][ka];
            const half8 bh0 = *(const half8*)&ldsEH[buf][rL + swz];
            const half8 bh1 = *(const half8*)&ldsEH[buf][rH + swz];
            const half8 bl0 = *(const half8*)&ldsEL[buf][rL + swz];
            const half8 bl1 = *(const half8*)&ldsEL[buf][rH + swz];
            acc_hh[0][0] = __builtin_amdgcn_mfma_f32_16x16x32_f16(ah0, bh0, acc_hh[0][0], 0, 0, 0);
            acc_hh[0][1] = __builtin_amdgcn_mfma_f32_16x16x32_f16(ah0, bh1, acc_hh[0][1], 0, 0, 0);
            acc_hh[1][0] = __builtin_amdgcn_mfma_f32_16x16x32_f16(ah1, bh0, acc_hh[1][0], 0, 0, 0);
            acc_hh[1][1] = __builtin_amdgcn_mfma_f32_16x16x32_f16(ah1, bh1, acc_hh[1][1], 0, 0, 0);
            acc_hl[0][0] = __builtin_amdgcn_mfma_f32_16x16x32_f16(ah0, bl0, acc_hl[0][0], 0, 0, 0);
            acc_hl[0][1] = __builtin_amdgcn_mfma_f32_16x16x32_f16(ah0, bl1, acc_hl[0][1], 0, 0, 0);
            acc_hl[1][0] = __builtin_amdgcn_mfma_f32_16x16x32_f16(ah1, bl0, acc_hl[1][0], 0, 0, 0);
            acc_hl[1][1] = __builtin_amdgcn_mfma_f32_16x16x32_f16(ah1, bl1, acc_hl[1][1], 0, 0, 0);
            acc_hl[0][0] = __builtin_amdgcn_mfma_f32_16x16x32_f16(al0, bh0, acc_hl[0][0], 0, 0, 0);
            acc_hl[0][1] = __builtin_amdgcn_mfma_f32_16x16x32_f16(al0, bh1, acc_hl[0][1], 0, 0, 0);
            acc_hl[1][0] = __builtin_amdgcn_mfma_f32_16x16x32_f16(al1, bh0, acc_hl[1][0], 0, 0, 0);
            acc_hl[1][1] = __builtin_amdgcn_mfma_f32_16x16x32_f16(al1, bh1, acc_hl[1][1], 0, 0, 0);
        }
        // ---- tile finalize: dist = fl(fl(s+se) - 2m), ascending code order ----
        if (ck == 3) {
            const int tb = (it >> 2) * CTILE;
            #pragma unroll
            for (int csi = 0; csi < 2; ++csi) {
                const float se   = csi ? se1 : se0;
                const int   code = tb + q32 + csi * 16 + ln;
                #pragma unroll
                for (int pbi = 0; pbi < 2; ++pbi)
                    #pragma unroll
                    for (int r = 0; r < 4; ++r) {
                        const float m  = fmaf(acc_hl[pbi][csi][r], 4.8828125e-4f,
                                              acc_hh[pbi][csi][r]) * 0.015625f;
                        const float T  = s_frag[pbi * 4 + r] + se;
                        const float dd = fmaf(-2.0f, m, T);
                        const int   s  = pbi * 4 + r;
                        if (dd < best_d[s]) { best_d[s] = dd; best_i[s] = code; }
                    }
            }
        }
    }

    // ---- argmin reduce: butterfly over the 16-lane col group (lexicographic) ----
    #pragma unroll
    for (int off = 1; off < 16; off <<= 1) {
        #pragma unroll
        for (int s = 0; s < 8; ++s) {
            const float d2 = __shfl_xor(best_d[s], off);
            const int   i2 = __shfl_xor(best_i[s], off);
            if (d2 < best_d[s] || (d2 == best_d[s] && i2 < best_i[s])) {
                best_d[s] = d2; best_i[s] = i2;
            }
        }
    }
    if (ln == 0) {
        #pragma unroll
        for (int pbi = 0; pbi < 2; ++pbi)
            #pragma unroll
            for (int r = 0; r < 4; ++r) {
                ldsFD[w][pbi * 16 + qd * 4 + r] = best_d[pbi * 4 + r];
                ldsFI[w][pbi * 16 + qd * 4 + r] = best_i[pbi * 4 + r];
            }
    }
    __syncthreads();
    if (t < PTB) {
        const int hh  = t >> 5;
        const int r32 = t & 31;
        float bd = 3.4e38f; int bi = 0;
        #pragma unroll
        for (int qq = 0; qq < 4; ++qq) {
            const int wv = hh + qq * 2;
            const float d2 = ldsFD[wv][r32];
            const int   i2 = ldsFI[wv][r32];
            if (d2 < bd || (d2 == bd && i2 < bi)) { bd = d2; bi = i2; }
        }
        ldsI[t] = bi;
        out[(size_t)IDX_OFF + n0 + t] = (float)bi;
    }
    __syncthreads();

    // ---- epilogue: gather e row, straight-through out, loss partial ----
    double lsum = 0.0;
    {
        const int p  = t & 63;
        const int cg = t >> 6;
        const int row = ldsI[p];
        const float* erow = emb + (size_t)row * DDIM;
        float* ob = out + (size_t)b * CHW + hw0 + p;
        for (int q = 0; q < 32; ++q) {
            const int c = cg * 32 + q;
            const float e  = erow[c];
            const float xx = xs[(size_t)c * HWSZ + p];
            const float diff = e - xx;             // fl(x_q - xt)
            ob[(size_t)c * HWSZ] = xx + diff;      // straight-through rounding
            lsum += (double)diff * (double)diff;
        }
    }
    #pragma unroll
    for (int off = 32; off > 0; off >>= 1)
        lsum += __shfl_xor(lsum, off);
    if ((t & 63) == 0) ldsL[t >> 6] = lsum;
    __syncthreads();
    if (t == 0) {
        double tot = 0.0;
        #pragma unroll
        for (int wv = 0; wv < 8; ++wv) tot += ldsL[wv];
        atomicAdd(&out[LOSS_OFF], (float)(tot * (1.25 / 4194304.0)));
    }
}

extern "C" void kernel_launch(void* const* d_in, const int* in_sizes, int n_in,
                              void* d_out, int out_size, void* d_ws, size_t ws_size,
                              hipStream_t stream) {
    (void)in_sizes; (void)n_in; (void)out_size; (void)ws_size;
    const float* x   = (const float*)d_in[0];
    const float* emb = (const float*)d_in[1];
    float* out = (float*)d_out;
    unsigned short* ehi = (unsigned short*)d_ws;
    unsigned short* elo = ehi + EHI_WORDS;
    float*          wse = (float*)((char*)d_ws + SE_OFF_B);
    hipMemsetAsync((char*)d_out + (size_t)LOSS_OFF * sizeof(float), 0, sizeof(float), stream);
    prep_kernel<<<256, 256, 0, stream>>>(emb, ehi, elo, wse);
    vq_kernel<<<NPTS / PTB, 512, 0, stream>>>(x, ehi, elo, wse, emb, out);
}